// Round 4
// baseline (475.663 us; speedup 1.0000x reference)
//
#include <hip/hip_runtime.h>
#include <hip/hip_bf16.h>
#include <math.h>

// Problem constants
#define Bn 16
#define Cc 256
#define Hh 64
#define Ww 64
#define HW 4096
#define C2 512
#define Pp 65536          // Bn*HW
#define EPSc 1e-5f

typedef __attribute__((ext_vector_type(8))) short short8;
typedef __attribute__((ext_vector_type(4))) float floatx4;

// ---------------------------------------------------------------------------
// Kernel 0: combine weights.
// W1[o,c]  = sum_m w_poly[o,m] * freq_real[m] * w_expand[m,c]
// W1g_b[o,c] = bf16(W1[o,c] * gamma[c])
// bias1[o] = sum_c W1[o,c] * beta[c]
// wsum[o]  = sum_c W1[o,c] * gamma[c]
// ---------------------------------------------------------------------------
__global__ __launch_bounds__(256)
void combine_weights(const float* __restrict__ w_expand,
                     const float* __restrict__ freq_real,
                     const float* __restrict__ w_poly,
                     const float* __restrict__ gamma,
                     const float* __restrict__ beta,
                     __hip_bfloat16* __restrict__ W1g_b,
                     float* __restrict__ bias1,
                     float* __restrict__ wsum) {
    int o = blockIdx.x;
    int c = threadIdx.x;
    float acc = 0.f;
    const float* wp = w_poly + (size_t)o * C2;
    for (int m = 0; m < C2; ++m) {
        acc += wp[m] * freq_real[m] * w_expand[(size_t)m * Cc + c];
    }
    float wg = acc * gamma[c];
    W1g_b[(size_t)o * Cc + c] = __float2bfloat16(wg);
    __shared__ float redB[256];
    __shared__ float redG[256];
    redB[c] = acc * beta[c];
    redG[c] = wg;
    __syncthreads();
    for (int s = 128; s > 0; s >>= 1) {
        if (c < s) { redB[c] += redB[c + s]; redG[c] += redG[c + s]; }
        __syncthreads();
    }
    if (c == 0) { bias1[o] = redB[0]; wsum[o] = redG[0]; }
}

// ---------------------------------------------------------------------------
// Kernel 0b: fp32 -> bf16 weight conversion (w_pw 512x512, w_final 256x512)
// ---------------------------------------------------------------------------
__global__ __launch_bounds__(256)
void to_bf16(const float* __restrict__ a, __hip_bfloat16* __restrict__ o, int n) {
    int i = (blockIdx.x * 256 + threadIdx.x) * 4;
    if (i < n) {
        float4 v = *(const float4*)&a[i];
        __hip_bfloat16 r[4];
        r[0] = __float2bfloat16(v.x);
        r[1] = __float2bfloat16(v.y);
        r[2] = __float2bfloat16(v.z);
        r[3] = __float2bfloat16(v.w);
        *(uint2*)&o[i] = *(const uint2*)r;
    }
}

// ---------------------------------------------------------------------------
// Kernel 0c: pad w_dw [512][9] -> [512][12] so taps load as 3 aligned float4
// ---------------------------------------------------------------------------
__global__ __launch_bounds__(256)
void pad_dw(const float* __restrict__ w_dw, float* __restrict__ w_dw_p) {
    int i = blockIdx.x * 256 + threadIdx.x;
    if (i < C2 * 12) {
        int k = i / 12, j = i - k * 12;
        w_dw_p[i] = (j < 9) ? w_dw[k * 9 + j] : 0.f;
    }
}

// ---------------------------------------------------------------------------
// Kernel 1: fused LN + GEMM1 (MFMA).
// f5[m,n] = r[n]*(G[m,n] - mu[n]*wsum[m]) + bias1[m],  G = W1g_bf16 @ x_raw.
// Staging loads fully hoisted into vreg[16] for HBM latency depth.
// ---------------------------------------------------------------------------
#define G1P 264   // LDS pitch in bf16 elems

__global__ __launch_bounds__(256, 2)
void gemm1_fused(const float* __restrict__ f,
                 const __hip_bfloat16* __restrict__ W1g_b,
                 const float* __restrict__ bias1,
                 const float* __restrict__ wsum,
                 __hip_bfloat16* __restrict__ f5) {
    __shared__ __hip_bfloat16 Bs[64 * G1P];   // raw x, [n][k], 33,792 B
    __shared__ float redS[16 * 64];
    __shared__ float redQ[16 * 64];
    __shared__ float mu_s[64], rs_s[64];

    int blk = blockIdx.x;          // 0..1023
    int p0 = blk * 64;
    int b = p0 >> 12;
    int s0 = p0 & 4095;
    int tid = threadIdx.x;
    int lane = tid & 63, wave = tid >> 6;
    int col = lane & 15, quad = lane >> 4;
    int x = tid & 15, g = tid >> 4;

    const float* fb = f + (size_t)b * Cc * HW + s0 + x * 4;

    // ---- bulk-issue all 16 staging loads (256 B/lane in flight) ----
    float4 v0r[8], v1r[8];
#pragma unroll
    for (int it = 0; it < 8; ++it) {
        int c = (it * 16 + g) * 2;
        v0r[it] = *(const float4*)&fb[(size_t)c * HW];
        v1r[it] = *(const float4*)&fb[(size_t)(c + 1) * HW];
    }

    // ---- stats + pack into Bs[n][k] ----
    float lsum[4] = {0.f, 0.f, 0.f, 0.f};
    float lsq[4]  = {0.f, 0.f, 0.f, 0.f};
    unsigned* dst = (unsigned*)&Bs[0];
#pragma unroll
    for (int it = 0; it < 8; ++it) {
        int cpair = it * 16 + g;           // 0..127
        float a0[4] = {v0r[it].x, v0r[it].y, v0r[it].z, v0r[it].w};
        float a1[4] = {v1r[it].x, v1r[it].y, v1r[it].z, v1r[it].w};
#pragma unroll
        for (int j = 0; j < 4; ++j) {
            lsum[j] += a0[j] + a1[j];
            lsq[j]  += a0[j] * a0[j] + a1[j] * a1[j];
            __hip_bfloat16 b0 = __float2bfloat16(a0[j]);
            __hip_bfloat16 b1 = __float2bfloat16(a1[j]);
            unsigned pk = ((unsigned)__bfloat16_as_ushort(b1) << 16) |
                          (unsigned)__bfloat16_as_ushort(b0);
            dst[(size_t)(x * 4 + j) * (G1P / 2) + cpair] = pk;
        }
    }
#pragma unroll
    for (int j = 0; j < 4; ++j) {
        redS[g * 64 + x * 4 + j] = lsum[j];
        redQ[g * 64 + x * 4 + j] = lsq[j];
    }

    // prefetch first A-frags (global, no LDS dep)
    int wm0 = wave * 128;
    const __hip_bfloat16* Ab = W1g_b + (size_t)(wm0 + col) * Cc + quad * 8;
    short8 a_cur[8], a_nxt[8];
#pragma unroll
    for (int mt = 0; mt < 8; ++mt)
        a_cur[mt] = *(const short8*)(Ab + (size_t)mt * 16 * Cc);

    __syncthreads();

    // reducers (wave 0): per-position mu / rstd
    if (tid < 64) {
        float s = 0.f, q = 0.f;
#pragma unroll
        for (int gg = 0; gg < 16; ++gg) {
            s += redS[gg * 64 + tid];
            q += redQ[gg * 64 + tid];
        }
        float m = s * (1.0f / 256.0f);
        mu_s[tid] = m;
        rs_s[tid] = rsqrtf(q * (1.0f / 256.0f) - m * m + EPSc);
    }

    // ---- MFMA: G = W1g @ x_raw, double-buffered A ----
    floatx4 acc[8][4];
#pragma unroll
    for (int mt = 0; mt < 8; ++mt)
#pragma unroll
        for (int nt = 0; nt < 4; ++nt)
            acc[mt][nt] = (floatx4){0.f, 0.f, 0.f, 0.f};

#pragma unroll
    for (int ks = 0; ks < 8; ++ks) {
        int k0 = ks * 32;
        if (ks < 7) {
#pragma unroll
            for (int mt = 0; mt < 8; ++mt)
                a_nxt[mt] = *(const short8*)(Ab + (size_t)mt * 16 * Cc + k0 + 32);
        }
        short8 bf[4];
#pragma unroll
        for (int nt = 0; nt < 4; ++nt)
            bf[nt] = *(const short8*)&Bs[(size_t)(nt * 16 + col) * G1P + k0 + quad * 8];
#pragma unroll
        for (int mt = 0; mt < 8; ++mt)
#pragma unroll
            for (int nt = 0; nt < 4; ++nt)
                acc[mt][nt] = __builtin_amdgcn_mfma_f32_16x16x32_bf16(
                    a_cur[mt], bf[nt], acc[mt][nt], 0, 0, 0);
        if (ks < 7) {
#pragma unroll
            for (int mt = 0; mt < 8; ++mt) a_cur[mt] = a_nxt[mt];
        }
    }

    __syncthreads();

    // ---- epilogue: f5 = (G - mu*wsum)*rstd + bias1 ----
    __hip_bfloat16* f5b = f5 + (size_t)b * C2 * HW + s0;
#pragma unroll
    for (int mt = 0; mt < 8; ++mt) {
        float bi[4], ws4[4];
#pragma unroll
        for (int r = 0; r < 4; ++r) {
            int m = wm0 + mt * 16 + quad * 4 + r;
            bi[r] = bias1[m];
            ws4[r] = wsum[m];
        }
#pragma unroll
        for (int nt = 0; nt < 4; ++nt) {
            int n = nt * 16 + col;
            float mn = mu_s[n], rn = rs_s[n];
#pragma unroll
            for (int r = 0; r < 4; ++r) {
                int m = wm0 + mt * 16 + quad * 4 + r;
                float v = (acc[mt][nt][r] - mn * ws4[r]) * rn + bi[r];
                f5b[(size_t)m * HW + n] = __float2bfloat16(v);
            }
        }
    }
}

// ---------------------------------------------------------------------------
// Kernel 3: fused tail. Phase-0 loads fully hoisted (24 uint4/lane in flight);
// halo via cross-lane __shfl within 4-lane groups; 1-of-4 lanes loads the
// single cross-tile boundary scalar (also hoisted).
// ---------------------------------------------------------------------------
#define TN3 32
#define TPITCH 520

__global__ __launch_bounds__(256, 3)
void fused_tail(const __hip_bfloat16* __restrict__ f5,
                const float* __restrict__ w_dw_p,
                const __hip_bfloat16* __restrict__ w_pw_b,
                const __hip_bfloat16* __restrict__ w_final_b,
                const float* __restrict__ f,
                float* __restrict__ out) {
    __shared__ __hip_bfloat16 tT[TN3 * TPITCH];   // 33,280 B, reused t -> f7

    int wt = blockIdx.x;       // 0..1
    int h  = blockIdx.y;       // 0..63
    int b  = blockIdx.z;       // 0..15
    int w0 = wt * TN3;
    int tid = threadIdx.x;
    int lane = tid & 63;
    int wave = tid >> 6;
    int col = lane & 15;
    int quad = lane >> 4;

    // ---- phase 0: depthwise 3x3 -> tT[n][k] (bf16) ----
    const __hip_bfloat16* f5b = f5 + (size_t)b * C2 * HW;
    int t3 = tid & 3;
    int kbase = tid >> 2;            // 0..63
    int n0 = t3 * 8;
    int w = w0 + n0;
    // cross-tile boundary scalar: wt=0 tile needs value at w=32 (lane t3==3),
    // wt=1 tile needs value at w=31 (lane t3==0). Outer image edges are zero.
    bool needL = (t3 == 0) && (wt == 1);
    bool needR = (t3 == 3) && (wt == 0);
    bool needE = needL || needR;
    int eoff = needL ? (w0 - 1) : (w0 + 32);   // 31 or 32/64(masked off)

    uint4 core[8][3];
    __hip_bfloat16 edgev[8][3];
    const __hip_bfloat16 bz = __float2bfloat16(0.f);
#pragma unroll
    for (int it = 0; it < 8; ++it) {
        int k = it * 64 + kbase;
#pragma unroll
        for (int dy = 0; dy < 3; ++dy) {
            int hh = h + dy - 1;
            if ((unsigned)hh < Hh) {
                const __hip_bfloat16* row = f5b + (size_t)k * HW + hh * Ww;
                core[it][dy] = *(const uint4*)&row[w];
                edgev[it][dy] = needE ? row[eoff] : bz;
            } else {
                core[it][dy] = make_uint4(0, 0, 0, 0);
                edgev[it][dy] = bz;
            }
        }
    }

    // consume: dwconv, write tT columns
#pragma unroll
    for (int it = 0; it < 8; ++it) {
        int k = it * 64 + kbase;
        const float4* wd4 = (const float4*)(w_dw_p + (size_t)k * 12);
        float4 wa = wd4[0], wb = wd4[1], wc = wd4[2];
        float wreg[9] = {wa.x, wa.y, wa.z, wa.w, wb.x, wb.y, wb.z, wb.w, wc.x};
        float acc8[8] = {};
#pragma unroll
        for (int dy = 0; dy < 3; ++dy) {
            const __hip_bfloat16* pv = (const __hip_bfloat16*)&core[it][dy];
            float cv[8];
#pragma unroll
            for (int j = 0; j < 8; ++j) cv[j] = __bfloat162float(pv[j]);
            float ev = __bfloat162float(edgev[it][dy]);
            float l_in = __shfl_up(cv[7], 1);
            float r_in = __shfl_down(cv[0], 1);
            if (t3 == 0) l_in = ev;
            if (t3 == 3) r_in = ev;
            float win[10];
            win[0] = l_in;
#pragma unroll
            for (int j = 0; j < 8; ++j) win[j + 1] = cv[j];
            win[9] = r_in;
#pragma unroll
            for (int j = 0; j < 8; ++j)
                acc8[j] += wreg[dy * 3 + 0] * win[j] +
                           wreg[dy * 3 + 1] * win[j + 1] +
                           wreg[dy * 3 + 2] * win[j + 2];
        }
#pragma unroll
        for (int j = 0; j < 8; ++j)
            tT[(n0 + j) * TPITCH + k] = __float2bfloat16(acc8[j]);
    }

    // ---- phase 1: g = w_pw @ t, A double-buffered from global ----
    int wm0 = wave * 128;
    const __hip_bfloat16* Ap = w_pw_b + (size_t)(wm0 + col) * C2 + quad * 8;
    short8 a_cur[8], a_nxt[8];
#pragma unroll
    for (int mt = 0; mt < 8; ++mt)
        a_cur[mt] = *(const short8*)(Ap + (size_t)mt * 16 * C2);

    __syncthreads();   // phase 0 done

    floatx4 acc[8][2];
#pragma unroll
    for (int mt = 0; mt < 8; ++mt) {
        acc[mt][0] = (floatx4){0.f, 0.f, 0.f, 0.f};
        acc[mt][1] = (floatx4){0.f, 0.f, 0.f, 0.f};
    }

#pragma unroll
    for (int ks = 0; ks < 16; ++ks) {
        int k0 = ks * 32;
        if (ks < 15) {
#pragma unroll
            for (int mt = 0; mt < 8; ++mt)
                a_nxt[mt] = *(const short8*)(Ap + (size_t)mt * 16 * C2 + k0 + 32);
        }
        short8 bf0 = *(const short8*)&tT[(size_t)col * TPITCH + k0 + quad * 8];
        short8 bf1 = *(const short8*)&tT[(size_t)(16 + col) * TPITCH + k0 + quad * 8];
#pragma unroll
        for (int mt = 0; mt < 8; ++mt) {
            acc[mt][0] = __builtin_amdgcn_mfma_f32_16x16x32_bf16(a_cur[mt], bf0, acc[mt][0], 0, 0, 0);
            acc[mt][1] = __builtin_amdgcn_mfma_f32_16x16x32_bf16(a_cur[mt], bf1, acc[mt][1], 0, 0, 0);
        }
        if (ks < 15) {
#pragma unroll
            for (int mt = 0; mt < 8; ++mt) a_cur[mt] = a_nxt[mt];
        }
    }
    __syncthreads();   // everyone done reading tT

    // ---- gating: f7 = gelu(g)*g -> back into tT (same [n][k] layout) ----
#pragma unroll
    for (int mt = 0; mt < 8; ++mt)
#pragma unroll
        for (int nt = 0; nt < 2; ++nt) {
            __hip_bfloat16 v4[4];
#pragma unroll
            for (int r = 0; r < 4; ++r) {
                float v = acc[mt][nt][r];
                float gl = 0.5f * v * (1.0f + erff(v * 0.70710678118f));
                v4[r] = __float2bfloat16(gl * v);
            }
            *(uint2*)&tT[(size_t)(nt * 16 + col) * TPITCH + wm0 + mt * 16 + quad * 4] = *(const uint2*)v4;
        }

    // ---- phase 2: f8 = w_final @ f7, A double-buffered ----
    int wm2 = wave * 64;
    const __hip_bfloat16* Af = w_final_b + (size_t)(wm2 + col) * C2 + quad * 8;
    short8 c_cur[4], c_nxt[4];
#pragma unroll
    for (int mt = 0; mt < 4; ++mt)
        c_cur[mt] = *(const short8*)(Af + (size_t)mt * 16 * C2);

    __syncthreads();   // f7 fully written

    floatx4 acc2[4][2];
#pragma unroll
    for (int mt = 0; mt < 4; ++mt) {
        acc2[mt][0] = (floatx4){0.f, 0.f, 0.f, 0.f};
        acc2[mt][1] = (floatx4){0.f, 0.f, 0.f, 0.f};
    }

#pragma unroll
    for (int ks = 0; ks < 16; ++ks) {
        int k0 = ks * 32;
        if (ks < 15) {
#pragma unroll
            for (int mt = 0; mt < 4; ++mt)
                c_nxt[mt] = *(const short8*)(Af + (size_t)mt * 16 * C2 + k0 + 32);
        }
        short8 bf0 = *(const short8*)&tT[(size_t)col * TPITCH + k0 + quad * 8];
        short8 bf1 = *(const short8*)&tT[(size_t)(16 + col) * TPITCH + k0 + quad * 8];
#pragma unroll
        for (int mt = 0; mt < 4; ++mt) {
            acc2[mt][0] = __builtin_amdgcn_mfma_f32_16x16x32_bf16(c_cur[mt], bf0, acc2[mt][0], 0, 0, 0);
            acc2[mt][1] = __builtin_amdgcn_mfma_f32_16x16x32_bf16(c_cur[mt], bf1, acc2[mt][1], 0, 0, 0);
        }
        if (ks < 15) {
#pragma unroll
            for (int mt = 0; mt < 4; ++mt) c_cur[mt] = c_nxt[mt];
        }
    }

    // ---- epilogue: out = f + f8 ----
    const float* fb = f + (size_t)b * Cc * HW + h * Ww + w0;
    float* ob = out + (size_t)b * Cc * HW + h * Ww + w0;
#pragma unroll
    for (int mt = 0; mt < 4; ++mt)
#pragma unroll
        for (int nt = 0; nt < 2; ++nt)
#pragma unroll
            for (int r = 0; r < 4; ++r) {
                int m = wm2 + mt * 16 + quad * 4 + r;
                int n = nt * 16 + col;
                size_t off = (size_t)m * HW + n;
                ob[off] = fb[off] + acc2[mt][nt][r];
            }
}

// ---------------------------------------------------------------------------
extern "C" void kernel_launch(void* const* d_in, const int* in_sizes, int n_in,
                              void* d_out, int out_size, void* d_ws, size_t ws_size,
                              hipStream_t stream) {
    const float* f         = (const float*)d_in[0];
    const float* ln_gamma  = (const float*)d_in[1];
    const float* ln_beta   = (const float*)d_in[2];
    const float* w_expand  = (const float*)d_in[3];
    const float* freq_real = (const float*)d_in[4];
    // d_in[5] = freq_imag: provably unused (Re((r+ij)*x) for real x = r*x)
    const float* w_poly    = (const float*)d_in[6];
    const float* w_dw      = (const float*)d_in[7];
    const float* w_pw      = (const float*)d_in[8];
    const float* w_final   = (const float*)d_in[9];
    float* out = (float*)d_out;

    // workspace layout
    char* ws = (char*)d_ws;
    __hip_bfloat16* f5 = (__hip_bfloat16*)ws;                       // 64 MiB
    char* p = ws + (size_t)67108864;
    __hip_bfloat16* W1g_b = (__hip_bfloat16*)p;  p += (size_t)C2 * Cc * 2;
    float* bias1 = (float*)p;                    p += (size_t)C2 * 4;
    float* wsum  = (float*)p;                    p += (size_t)C2 * 4;
    __hip_bfloat16* w_pw_b    = (__hip_bfloat16*)p;  p += (size_t)C2 * C2 * 2;
    __hip_bfloat16* w_final_b = (__hip_bfloat16*)p;  p += (size_t)Cc * C2 * 2;
    float* w_dw_p = (float*)p;                   p += (size_t)C2 * 12 * 4;

    combine_weights<<<dim3(C2), dim3(256), 0, stream>>>(
        w_expand, freq_real, w_poly, ln_gamma, ln_beta, W1g_b, bias1, wsum);

    to_bf16<<<dim3((C2 * C2 / 4 + 255) / 256), dim3(256), 0, stream>>>(
        w_pw, w_pw_b, C2 * C2);
    to_bf16<<<dim3((Cc * C2 / 4 + 255) / 256), dim3(256), 0, stream>>>(
        w_final, w_final_b, Cc * C2);
    pad_dw<<<dim3((C2 * 12 + 255) / 256), dim3(256), 0, stream>>>(w_dw, w_dw_p);

    gemm1_fused<<<dim3(Pp / 64), dim3(256), 0, stream>>>(
        f, W1g_b, bias1, wsum, f5);

    fused_tail<<<dim3(Ww / TN3, Hh, Bn), dim3(256), 0, stream>>>(
        f5, w_dw_p, w_pw_b, w_final_b, f, out);
}

// Round 5
// 447.000 us; speedup vs baseline: 1.0641x; 1.0641x over previous
//
#include <hip/hip_runtime.h>
#include <hip/hip_bf16.h>
#include <math.h>

// Problem constants
#define Bn 16
#define Cc 256
#define Hh 64
#define Ww 64
#define HW 4096
#define C2 512
#define Pp 65536          // Bn*HW
#define EPSc 1e-5f

typedef __attribute__((ext_vector_type(8))) short short8;
typedef __attribute__((ext_vector_type(4))) float floatx4;

// ---------------------------------------------------------------------------
// Kernel 0: combine weights.
// W1[o,c]  = sum_m w_poly[o,m] * freq_real[m] * w_expand[m,c]
// W1g_b[o,c] = bf16(W1[o,c] * gamma[c]);  bias1[o] = sum_c W1*beta;
// wsum[o] = sum_c W1*gamma
// ---------------------------------------------------------------------------
__global__ __launch_bounds__(256)
void combine_weights(const float* __restrict__ w_expand,
                     const float* __restrict__ freq_real,
                     const float* __restrict__ w_poly,
                     const float* __restrict__ gamma,
                     const float* __restrict__ beta,
                     __hip_bfloat16* __restrict__ W1g_b,
                     float* __restrict__ bias1,
                     float* __restrict__ wsum) {
    int o = blockIdx.x;
    int c = threadIdx.x;
    float acc = 0.f;
    const float* wp = w_poly + (size_t)o * C2;
    for (int m = 0; m < C2; ++m) {
        acc += wp[m] * freq_real[m] * w_expand[(size_t)m * Cc + c];
    }
    float wg = acc * gamma[c];
    W1g_b[(size_t)o * Cc + c] = __float2bfloat16(wg);
    __shared__ float redB[256];
    __shared__ float redG[256];
    redB[c] = acc * beta[c];
    redG[c] = wg;
    __syncthreads();
    for (int s = 128; s > 0; s >>= 1) {
        if (c < s) { redB[c] += redB[c + s]; redG[c] += redG[c + s]; }
        __syncthreads();
    }
    if (c == 0) { bias1[o] = redB[0]; wsum[o] = redG[0]; }
}

// ---------------------------------------------------------------------------
// Kernel 0b: fp32 -> bf16 weight conversion
// ---------------------------------------------------------------------------
__global__ __launch_bounds__(256)
void to_bf16(const float* __restrict__ a, __hip_bfloat16* __restrict__ o, int n) {
    int i = (blockIdx.x * 256 + threadIdx.x) * 4;
    if (i < n) {
        float4 v = *(const float4*)&a[i];
        __hip_bfloat16 r[4];
        r[0] = __float2bfloat16(v.x);
        r[1] = __float2bfloat16(v.y);
        r[2] = __float2bfloat16(v.z);
        r[3] = __float2bfloat16(v.w);
        *(uint2*)&o[i] = *(const uint2*)r;
    }
}

// ---------------------------------------------------------------------------
// Kernel 0c: pad w_dw [512][9] -> [512][12]
// ---------------------------------------------------------------------------
__global__ __launch_bounds__(256)
void pad_dw(const float* __restrict__ w_dw, float* __restrict__ w_dw_p) {
    int i = blockIdx.x * 256 + threadIdx.x;
    if (i < C2 * 12) {
        int k = i / 12, j = i - k * 12;
        w_dw_p[i] = (j < 9) ? w_dw[k * 9 + j] : 0.f;
    }
}

// ---------------------------------------------------------------------------
// Kernel 1: prep_x — read f (NCHW fp32), emit x_bf (NHWC bf16, k-contiguous)
// + per-position LN stats mu/rstd. Block = 64 positions.
// ---------------------------------------------------------------------------
#define XP 264   // LDS row pitch in bf16 (528 B, 16B-aligned, bank-shifted)

__global__ __launch_bounds__(256, 3)
void prep_x(const float* __restrict__ f,
            __hip_bfloat16* __restrict__ x_bf,
            float* __restrict__ muA,
            float* __restrict__ rsA) {
    __shared__ __hip_bfloat16 Bs[64 * XP];    // 33,792 B, [n][k]
    __shared__ float redS[1024], redQ[1024];

    int blk = blockIdx.x;          // 0..1023
    int b = blk >> 6;
    int s0 = (blk & 63) << 6;
    int tid = threadIdx.x;
    int x = tid & 15, g = tid >> 4;

    const float* fb = f + (size_t)b * Cc * HW + s0 + x * 4;

    float4 v0r[8], v1r[8];
#pragma unroll
    for (int it = 0; it < 8; ++it) {
        int c = (it * 16 + g) * 2;
        v0r[it] = *(const float4*)&fb[(size_t)c * HW];
        v1r[it] = *(const float4*)&fb[(size_t)(c + 1) * HW];
    }

    float lsum[4] = {0.f, 0.f, 0.f, 0.f};
    float lsq[4]  = {0.f, 0.f, 0.f, 0.f};
    unsigned* dst = (unsigned*)&Bs[0];
#pragma unroll
    for (int it = 0; it < 8; ++it) {
        int cpair = it * 16 + g;
        float a0[4] = {v0r[it].x, v0r[it].y, v0r[it].z, v0r[it].w};
        float a1[4] = {v1r[it].x, v1r[it].y, v1r[it].z, v1r[it].w};
#pragma unroll
        for (int j = 0; j < 4; ++j) {
            lsum[j] += a0[j] + a1[j];
            lsq[j]  += a0[j] * a0[j] + a1[j] * a1[j];
            __hip_bfloat16 b0 = __float2bfloat16(a0[j]);
            __hip_bfloat16 b1 = __float2bfloat16(a1[j]);
            unsigned pk = ((unsigned)__bfloat16_as_ushort(b1) << 16) |
                          (unsigned)__bfloat16_as_ushort(b0);
            dst[(size_t)(x * 4 + j) * (XP / 2) + cpair] = pk;
        }
    }
#pragma unroll
    for (int j = 0; j < 4; ++j) {
        redS[g * 64 + x * 4 + j] = lsum[j];
        redQ[g * 64 + x * 4 + j] = lsq[j];
    }
    __syncthreads();

    if (tid < 64) {
        float s = 0.f, q = 0.f;
#pragma unroll
        for (int gg = 0; gg < 16; ++gg) {
            s += redS[gg * 64 + tid];
            q += redQ[gg * 64 + tid];
        }
        float m = s * (1.0f / 256.0f);
        int p = blk * 64 + tid;
        muA[p] = m;
        rsA[p] = rsqrtf(q * (1.0f / 256.0f) - m * m + EPSc);
    }

    // coalesced copy LDS -> global NHWC
    int n = tid >> 2, q4 = tid & 3;
    const __hip_bfloat16* src = &Bs[(size_t)n * XP + q4 * 64];
    __hip_bfloat16* gout = x_bf + ((size_t)blk * 64 + n) * Cc + q4 * 64;
#pragma unroll
    for (int i = 0; i < 8; ++i)
        *(uint4*)&gout[i * 8] = *(const uint4*)&src[i * 8];
}

// ---------------------------------------------------------------------------
// Kernel 2: gemm1b — m97-style 2-barrier GEMM, swapped operands.
// D[p][c] = sum_k x_bf[p,k] * W1g_b[c,k];  f5 = (D - mu[p]*wsum[c])*rstd[p]+bias1[c]
// Block: 128 p x 128 c, K=256, BK=32, 4 waves (2x2 of 64x64). f5 NCHW bf16.
// ---------------------------------------------------------------------------
__global__ __launch_bounds__(256, 3)
void gemm1b(const __hip_bfloat16* __restrict__ x_bf,
            const __hip_bfloat16* __restrict__ W1g_b,
            const float* __restrict__ bias1,
            const float* __restrict__ wsum,
            const float* __restrict__ muA,
            const float* __restrict__ rsA,
            __hip_bfloat16* __restrict__ f5) {
    __shared__ __hip_bfloat16 As[128 * 32];   // 8 KB [p-row][32k]
    __shared__ __hip_bfloat16 Ws[128 * 32];   // 8 KB [c-row][32k]

    int flat = blockIdx.x;         // 0..2047
    int ct = flat & 3;
    int pt = flat >> 2;            // 0..511
    int p0 = pt * 128, c0 = ct * 128;
    int tid = threadIdx.x;
    int lane = tid & 63, wave = tid >> 6;
    int col = lane & 15, quad = lane >> 4;
    int wp = wave >> 1, wc = wave & 1;        // wave tile: 64p x 64c

    floatx4 acc[4][4];
#pragma unroll
    for (int i = 0; i < 4; ++i)
#pragma unroll
        for (int j = 0; j < 4; ++j)
            acc[i][j] = (floatx4){0.f, 0.f, 0.f, 0.f};

    int row0 = tid >> 2, part0 = tid & 3;          // staging slot 0
    int idx1 = 256 + tid;
    int row1 = idx1 >> 2, part1 = idx1 & 3;        // staging slot 1

    for (int ks = 0; ks < 8; ++ks) {
        int k0 = ks * 32;
        // global loads (registers) — independent of LDS
        uint4 ga0 = *(const uint4*)&x_bf[((size_t)(p0 + row0)) * Cc + k0 + part0 * 8];
        uint4 ga1 = *(const uint4*)&x_bf[((size_t)(p0 + row1)) * Cc + k0 + part1 * 8];
        uint4 gb0 = *(const uint4*)&W1g_b[((size_t)(c0 + row0)) * Cc + k0 + part0 * 8];
        uint4 gb1 = *(const uint4*)&W1g_b[((size_t)(c0 + row1)) * Cc + k0 + part1 * 8];
        if (ks > 0) __syncthreads();   // all waves done reading previous tile
        *(uint4*)&As[(size_t)row0 * 32 + part0 * 8] = ga0;
        *(uint4*)&As[(size_t)row1 * 32 + part1 * 8] = ga1;
        *(uint4*)&Ws[(size_t)row0 * 32 + part0 * 8] = gb0;
        *(uint4*)&Ws[(size_t)row1 * 32 + part1 * 8] = gb1;
        __syncthreads();

        short8 af[4], bf[4];
#pragma unroll
        for (int i = 0; i < 4; ++i)
            af[i] = *(const short8*)&As[(size_t)(wp * 64 + i * 16 + col) * 32 + quad * 8];
#pragma unroll
        for (int j = 0; j < 4; ++j)
            bf[j] = *(const short8*)&Ws[(size_t)(wc * 64 + j * 16 + col) * 32 + quad * 8];
#pragma unroll
        for (int i = 0; i < 4; ++i)
#pragma unroll
            for (int j = 0; j < 4; ++j)
                acc[i][j] = __builtin_amdgcn_mfma_f32_16x16x32_bf16(af[i], bf[j], acc[i][j], 0, 0, 0);
    }

    // epilogue: affine + packed uint2 stores (4 consecutive positions/lane)
    int b2 = p0 >> 12;
    int sbase = p0 & 4095;
#pragma unroll
    for (int i = 0; i < 4; ++i) {
        int pl = wp * 64 + i * 16 + quad * 4;          // local p of reg 0
        float4 mu4 = *(const float4*)&muA[p0 + pl];
        float4 rs4 = *(const float4*)&rsA[p0 + pl];
        float mu_[4] = {mu4.x, mu4.y, mu4.z, mu4.w};
        float rs_[4] = {rs4.x, rs4.y, rs4.z, rs4.w};
#pragma unroll
        for (int j = 0; j < 4; ++j) {
            int c = c0 + wc * 64 + j * 16 + col;
            float ws_ = wsum[c], bi_ = bias1[c];
            __hip_bfloat16 v4[4];
#pragma unroll
            for (int r = 0; r < 4; ++r) {
                float v = (acc[i][j][r] - mu_[r] * ws_) * rs_[r] + bi_;
                v4[r] = __float2bfloat16(v);
            }
            *(uint2*)&f5[((size_t)b2 * C2 + c) * HW + sbase + pl] = *(const uint2*)v4;
        }
    }
}

// ---------------------------------------------------------------------------
// Kernel 3: fused tail. Phase-0 depth-2 ping-pong (no spill); XCD h-band
// swizzle for f5 L2 reuse; residual loads hoisted above phase-2 MFMA.
// ---------------------------------------------------------------------------
#define TN3 32
#define TPITCH 520

__global__ __launch_bounds__(256, 3)
void fused_tail(const __hip_bfloat16* __restrict__ f5,
                const float* __restrict__ w_dw_p,
                const __hip_bfloat16* __restrict__ w_pw_b,
                const __hip_bfloat16* __restrict__ w_final_b,
                const float* __restrict__ f,
                float* __restrict__ out) {
    __shared__ __hip_bfloat16 tT[TN3 * TPITCH];   // 33,280 B, reused t -> f7

    // XCD-aware swizzle: 8 consecutive flat ids -> 8 XCDs; each XCD owns an
    // 8-row h-band, iterating b slowest so the band's f5 slab stays in its L2.
    int flat = blockIdx.x;         // 0..2047
    int xcd = flat & 7;
    int slot = flat >> 3;          // 0..255
    int wt = slot & 1;
    int hb = (slot >> 1) & 7;
    int b  = slot >> 4;            // 0..15
    int h  = xcd * 8 + hb;

    int w0 = wt * TN3;
    int tid = threadIdx.x;
    int lane = tid & 63;
    int wave = tid >> 6;
    int col = lane & 15;
    int quad = lane >> 4;

    // ---- phase 0: depthwise 3x3 -> tT[n][k] (bf16), depth-2 pipeline ----
    const __hip_bfloat16* f5b = f5 + (size_t)b * C2 * HW;
    int t3 = tid & 3;
    int kbase = tid >> 2;            // 0..63
    int n0 = t3 * 8;
    int w = w0 + n0;
    bool needL = (t3 == 0) && (wt == 1);
    bool needR = (t3 == 3) && (wt == 0);
    bool needE = needL || needR;
    int eoff = needL ? (w0 - 1) : (w0 + 32);
    const __hip_bfloat16 bz = __float2bfloat16(0.f);

    uint4 curC[3]; __hip_bfloat16 curE[3];
    uint4 nxtC[3]; __hip_bfloat16 nxtE[3];

#pragma unroll
    for (int dy = 0; dy < 3; ++dy) {
        int hh = h + dy - 1;
        if ((unsigned)hh < Hh) {
            const __hip_bfloat16* row = f5b + (size_t)kbase * HW + hh * Ww;
            curC[dy] = *(const uint4*)&row[w];
            curE[dy] = needE ? row[eoff] : bz;
        } else { curC[dy] = make_uint4(0,0,0,0); curE[dy] = bz; }
    }

#pragma unroll
    for (int it = 0; it < 8; ++it) {
        if (it < 7) {
            int k = (it + 1) * 64 + kbase;
#pragma unroll
            for (int dy = 0; dy < 3; ++dy) {
                int hh = h + dy - 1;
                if ((unsigned)hh < Hh) {
                    const __hip_bfloat16* row = f5b + (size_t)k * HW + hh * Ww;
                    nxtC[dy] = *(const uint4*)&row[w];
                    nxtE[dy] = needE ? row[eoff] : bz;
                } else { nxtC[dy] = make_uint4(0,0,0,0); nxtE[dy] = bz; }
            }
        }
        // consume current
        int k = it * 64 + kbase;
        const float4* wd4 = (const float4*)(w_dw_p + (size_t)k * 12);
        float4 wa = wd4[0], wb = wd4[1], wc2 = wd4[2];
        float wreg[9] = {wa.x, wa.y, wa.z, wa.w, wb.x, wb.y, wb.z, wb.w, wc2.x};
        float acc8[8] = {};
#pragma unroll
        for (int dy = 0; dy < 3; ++dy) {
            const __hip_bfloat16* pv = (const __hip_bfloat16*)&curC[dy];
            float cv[8];
#pragma unroll
            for (int j = 0; j < 8; ++j) cv[j] = __bfloat162float(pv[j]);
            float ev = __bfloat162float(curE[dy]);
            float l_in = __shfl_up(cv[7], 1);
            float r_in = __shfl_down(cv[0], 1);
            if (t3 == 0) l_in = ev;
            if (t3 == 3) r_in = ev;
            float win[10];
            win[0] = l_in;
#pragma unroll
            for (int j = 0; j < 8; ++j) win[j + 1] = cv[j];
            win[9] = r_in;
#pragma unroll
            for (int j = 0; j < 8; ++j)
                acc8[j] += wreg[dy * 3 + 0] * win[j] +
                           wreg[dy * 3 + 1] * win[j + 1] +
                           wreg[dy * 3 + 2] * win[j + 2];
        }
#pragma unroll
        for (int j = 0; j < 8; ++j)
            tT[(n0 + j) * TPITCH + k] = __float2bfloat16(acc8[j]);
        if (it < 7) {
#pragma unroll
            for (int dy = 0; dy < 3; ++dy) { curC[dy] = nxtC[dy]; curE[dy] = nxtE[dy]; }
        }
    }

    // ---- phase 1: g = w_pw @ t, A double-buffered from global ----
    int wm0 = wave * 128;
    const __hip_bfloat16* Ap = w_pw_b + (size_t)(wm0 + col) * C2 + quad * 8;
    short8 a_cur[8], a_nxt[8];
#pragma unroll
    for (int mt = 0; mt < 8; ++mt)
        a_cur[mt] = *(const short8*)(Ap + (size_t)mt * 16 * C2);

    __syncthreads();   // phase 0 done

    floatx4 acc[8][2];
#pragma unroll
    for (int mt = 0; mt < 8; ++mt) {
        acc[mt][0] = (floatx4){0.f, 0.f, 0.f, 0.f};
        acc[mt][1] = (floatx4){0.f, 0.f, 0.f, 0.f};
    }

#pragma unroll
    for (int ks = 0; ks < 16; ++ks) {
        int k0 = ks * 32;
        if (ks < 15) {
#pragma unroll
            for (int mt = 0; mt < 8; ++mt)
                a_nxt[mt] = *(const short8*)(Ap + (size_t)mt * 16 * C2 + k0 + 32);
        }
        short8 bf0 = *(const short8*)&tT[(size_t)col * TPITCH + k0 + quad * 8];
        short8 bf1 = *(const short8*)&tT[(size_t)(16 + col) * TPITCH + k0 + quad * 8];
#pragma unroll
        for (int mt = 0; mt < 8; ++mt) {
            acc[mt][0] = __builtin_amdgcn_mfma_f32_16x16x32_bf16(a_cur[mt], bf0, acc[mt][0], 0, 0, 0);
            acc[mt][1] = __builtin_amdgcn_mfma_f32_16x16x32_bf16(a_cur[mt], bf1, acc[mt][1], 0, 0, 0);
        }
        if (ks < 15) {
#pragma unroll
            for (int mt = 0; mt < 8; ++mt) a_cur[mt] = a_nxt[mt];
        }
    }
    __syncthreads();   // everyone done reading tT

    // ---- gating: f7 = gelu(g)*g -> back into tT ----
#pragma unroll
    for (int mt = 0; mt < 8; ++mt)
#pragma unroll
        for (int nt = 0; nt < 2; ++nt) {
            __hip_bfloat16 v4[4];
#pragma unroll
            for (int r = 0; r < 4; ++r) {
                float v = acc[mt][nt][r];
                float gl = 0.5f * v * (1.0f + erff(v * 0.70710678118f));
                v4[r] = __float2bfloat16(gl * v);
            }
            *(uint2*)&tT[(size_t)(nt * 16 + col) * TPITCH + wm0 + mt * 16 + quad * 4] = *(const uint2*)v4;
        }

    // ---- phase 2: f8 = w_final @ f7; residual loads hoisted ----
    int wm2 = wave * 64;
    const __hip_bfloat16* Af = w_final_b + (size_t)(wm2 + col) * C2 + quad * 8;
    short8 c_cur[4], c_nxt[4];
#pragma unroll
    for (int mt = 0; mt < 4; ++mt)
        c_cur[mt] = *(const short8*)(Af + (size_t)mt * 16 * C2);

    const float* fb = f + (size_t)b * Cc * HW + h * Ww + w0;
    float* ob = out + (size_t)b * Cc * HW + h * Ww + w0;
    float fres[4][2][4];
#pragma unroll
    for (int mt = 0; mt < 4; ++mt)
#pragma unroll
        for (int nt = 0; nt < 2; ++nt)
#pragma unroll
            for (int r = 0; r < 4; ++r) {
                int m = wm2 + mt * 16 + quad * 4 + r;
                int n = nt * 16 + col;
                fres[mt][nt][r] = fb[(size_t)m * HW + n];
            }

    __syncthreads();   // f7 fully written

    floatx4 acc2[4][2];
#pragma unroll
    for (int mt = 0; mt < 4; ++mt) {
        acc2[mt][0] = (floatx4){0.f, 0.f, 0.f, 0.f};
        acc2[mt][1] = (floatx4){0.f, 0.f, 0.f, 0.f};
    }

#pragma unroll
    for (int ks = 0; ks < 16; ++ks) {
        int k0 = ks * 32;
        if (ks < 15) {
#pragma unroll
            for (int mt = 0; mt < 4; ++mt)
                c_nxt[mt] = *(const short8*)(Af + (size_t)mt * 16 * C2 + k0 + 32);
        }
        short8 bf0 = *(const short8*)&tT[(size_t)col * TPITCH + k0 + quad * 8];
        short8 bf1 = *(const short8*)&tT[(size_t)(16 + col) * TPITCH + k0 + quad * 8];
#pragma unroll
        for (int mt = 0; mt < 4; ++mt) {
            acc2[mt][0] = __builtin_amdgcn_mfma_f32_16x16x32_bf16(c_cur[mt], bf0, acc2[mt][0], 0, 0, 0);
            acc2[mt][1] = __builtin_amdgcn_mfma_f32_16x16x32_bf16(c_cur[mt], bf1, acc2[mt][1], 0, 0, 0);
        }
        if (ks < 15) {
#pragma unroll
            for (int mt = 0; mt < 4; ++mt) c_cur[mt] = c_nxt[mt];
        }
    }

    // ---- epilogue: out = f + f8 ----
#pragma unroll
    for (int mt = 0; mt < 4; ++mt)
#pragma unroll
        for (int nt = 0; nt < 2; ++nt)
#pragma unroll
            for (int r = 0; r < 4; ++r) {
                int m = wm2 + mt * 16 + quad * 4 + r;
                int n = nt * 16 + col;
                ob[(size_t)m * HW + n] = fres[mt][nt][r] + acc2[mt][nt][r];
            }
}

// ---------------------------------------------------------------------------
extern "C" void kernel_launch(void* const* d_in, const int* in_sizes, int n_in,
                              void* d_out, int out_size, void* d_ws, size_t ws_size,
                              hipStream_t stream) {
    const float* f         = (const float*)d_in[0];
    const float* ln_gamma  = (const float*)d_in[1];
    const float* ln_beta   = (const float*)d_in[2];
    const float* w_expand  = (const float*)d_in[3];
    const float* freq_real = (const float*)d_in[4];
    // d_in[5] = freq_imag: provably unused (Re((r+ij)*x) for real x = r*x)
    const float* w_poly    = (const float*)d_in[6];
    const float* w_dw      = (const float*)d_in[7];
    const float* w_pw      = (const float*)d_in[8];
    const float* w_final   = (const float*)d_in[9];
    float* out = (float*)d_out;

    // workspace layout (<= ~66 MB, fits prior footprint)
    char* p = (char*)d_ws;
    __hip_bfloat16* f5   = (__hip_bfloat16*)p;  p += (size_t)C2 * Pp * 2;   // 64... 32 MiB
    __hip_bfloat16* x_bf = (__hip_bfloat16*)p;  p += (size_t)Cc * Pp * 2;   // 32 MiB
    __hip_bfloat16* W1g_b = (__hip_bfloat16*)p; p += (size_t)C2 * Cc * 2;
    float* bias1 = (float*)p;                   p += (size_t)C2 * 4;
    float* wsum  = (float*)p;                   p += (size_t)C2 * 4;
    float* muA   = (float*)p;                   p += (size_t)Pp * 4;
    float* rsA   = (float*)p;                   p += (size_t)Pp * 4;
    __hip_bfloat16* w_pw_b    = (__hip_bfloat16*)p;  p += (size_t)C2 * C2 * 2;
    __hip_bfloat16* w_final_b = (__hip_bfloat16*)p;  p += (size_t)Cc * C2 * 2;
    float* w_dw_p = (float*)p;                  p += (size_t)C2 * 12 * 4;

    combine_weights<<<dim3(C2), dim3(256), 0, stream>>>(
        w_expand, freq_real, w_poly, ln_gamma, ln_beta, W1g_b, bias1, wsum);

    to_bf16<<<dim3((C2 * C2 / 4 + 255) / 256), dim3(256), 0, stream>>>(
        w_pw, w_pw_b, C2 * C2);
    to_bf16<<<dim3((Cc * C2 / 4 + 255) / 256), dim3(256), 0, stream>>>(
        w_final, w_final_b, Cc * C2);
    pad_dw<<<dim3((C2 * 12 + 255) / 256), dim3(256), 0, stream>>>(w_dw, w_dw_p);

    prep_x<<<dim3(Pp / 64), dim3(256), 0, stream>>>(f, x_bf, muA, rsA);

    gemm1b<<<dim3(2048), dim3(256), 0, stream>>>(
        x_bf, W1g_b, bias1, wsum, muA, rsA, f5);

    fused_tail<<<dim3(2048), dim3(256), 0, stream>>>(
        f5, w_dw_p, w_pw_b, w_final_b, f, out);
}